// Round 10
// baseline (225.998 us; speedup 1.0000x reference)
//
#include <hip/hip_runtime.h>
#include <math.h>

namespace {

constexpr int B_ = 4;
constexpr int C_ = 256;
constexpr int C4_ = 64;
constexpr int N_ = 4096;

typedef __attribute__((ext_vector_type(8))) short bf16x8;
typedef __attribute__((ext_vector_type(4))) float f32x4;
typedef __attribute__((ext_vector_type(16))) float f32x16;

__device__ __forceinline__ unsigned short bf16_rne(float f) {
    unsigned u = __float_as_uint(f);
    u += 0x7fffu + ((u >> 16) & 1u);
    return (unsigned short)(u >> 16);
}

__device__ __forceinline__ float bf16_to_f(unsigned short s) {
    return __uint_as_float(((unsigned)s) << 16);
}

// Async global->LDS DMA, 16B per lane. LDS dest = wave-uniform base + lane*16.
__device__ __forceinline__ void g2l16(const unsigned short* g, unsigned short* l) {
    __builtin_amdgcn_global_load_lds(
        (const __attribute__((address_space(1))) unsigned int*)g,
        (__attribute__((address_space(3))) unsigned int*)l, 16, 0, 0);
}

// Convert wq||wv -> wfrag (per-lane MFMA B-fragment order), wt -> wtb.
__global__ __launch_bounds__(256) void cvt_kernel(
        const float* __restrict__ wq, const float* __restrict__ wv,
        const float* __restrict__ wt, unsigned short* __restrict__ wfrag,
        unsigned short* __restrict__ wtb) {
    const int i = (blockIdx.x * 256 + threadIdx.x) * 4;
    const float* src;
    unsigned short* dst;
    if (i < 81920) {
        src = (i < 16384) ? (wq + i) : (wv + (i - 16384));
        const int o = i >> 8, c = i & 255;
        const int gro = o >> 4, l15 = o & 15;
        const int ch = c >> 5, quad = (c >> 3) & 3, e = c & 7;
        dst = wfrag + (((gro * 8 + ch) * 64 + quad * 16 + l15) * 8 + e);
    } else {
        src = wt + (i - 81920);
        dst = wtb + (i - 81920);
    }
    const float4 f = *reinterpret_cast<const float4*>(src);
    ushort4 u;
    u.x = bf16_rne(f.x); u.y = bf16_rne(f.y);
    u.z = bf16_rne(f.z); u.w = bf16_rne(f.w);
    *reinterpret_cast<ushort4*>(dst) = u;
}

// MFMA projection (unchanged).
__global__ __launch_bounds__(1024, 4) void proj_kernel(
        const float* __restrict__ x, const unsigned short* __restrict__ wfragb,
        const float* __restrict__ bv, unsigned short* __restrict__ qkT,
        unsigned short* __restrict__ v) {
    __shared__ unsigned short xs[2][64][42];
    const int b = blockIdx.y;
    const int n0 = blockIdx.x * 64;
    const int tid = threadIdx.x;
    const int wave = tid >> 6, lane = tid & 63;
    const int ws = wave & 3, oq = wave >> 2;
    const int quad = lane >> 4, l15 = lane & 15;
    const int ca = tid >> 6, na = tid & 63;
    const int cb = (tid + 1024) >> 6, nb2 = (tid + 1024) & 63;
    f32x4 acc[5];
#pragma unroll
    for (int ot = 0; ot < 5; ++ot) acc[ot] = (f32x4){0.f, 0.f, 0.f, 0.f};
    xs[0][na][ca] = bf16_rne(x[((size_t)b * C_ + ca) * N_ + n0 + na]);
    xs[0][nb2][cb] = bf16_rne(x[((size_t)b * C_ + cb) * N_ + n0 + nb2]);
    __syncthreads();
    for (int ch = 0; ch < 8; ++ch) {
        const int buf = ch & 1;
        float la = 0.f, lb = 0.f;
        if (ch < 7) {
            la = x[((size_t)b * C_ + (ch + 1) * 32 + ca) * N_ + n0 + na];
            lb = x[((size_t)b * C_ + (ch + 1) * 32 + cb) * N_ + n0 + nb2];
        }
        const bf16x8 a = *reinterpret_cast<const bf16x8*>(&xs[buf][ws * 16 + l15][quad * 8]);
#pragma unroll
        for (int ot = 0; ot < 5; ++ot) {
            const int gro = oq * 5 + ot;
            const bf16x8 wb = *reinterpret_cast<const bf16x8*>(
                wfragb + (size_t)(((gro * 8 + ch) * 64 + lane) * 8));
            acc[ot] = __builtin_amdgcn_mfma_f32_16x16x32_bf16(a, wb, acc[ot], 0, 0, 0);
        }
        if (ch < 7) {
            xs[buf ^ 1][na][ca] = bf16_rne(la);
            xs[buf ^ 1][nb2][cb] = bf16_rne(lb);
        }
        __syncthreads();
    }
    const int n = n0 + ws * 16 + quad * 4;
#pragma unroll
    for (int ot = 0; ot < 5; ++ot) {
        const int gro = oq * 5 + ot;
        if (gro < 4) {
            const int o = gro * 16 + l15;
#pragma unroll
            for (int r = 0; r < 4; ++r)
                qkT[((size_t)b * N_ + n + r) * C4_ + o] = bf16_rne(acc[ot][r]);
        } else {
            const int c = (gro - 4) * 16 + l15;
            const float bb = bv[c];
            ushort4 u;
            u.x = bf16_rne(acc[ot][0] + bb);
            u.y = bf16_rne(acc[ot][1] + bb);
            u.z = bf16_rne(acc[ot][2] + bb);
            u.w = bf16_rne(acc[ot][3] + bb);
            *reinterpret_cast<ushort4*>(&v[((size_t)b * C_ + c) * N_ + n]) = u;
        }
    }
}

// rowsum_e: rowsuminv + E~[n][m] = bf16(exp(e)) materialization + per-block
// weighted column partials psum[b][blk][m] = sum_n E~ * rsuminv[n].
// 32x32 MFMA scan (verified), E~ transpose/store machinery copied from the
// verified colsum WP path, stores folded into counted vmcnt (steady 4).
__global__ __launch_bounds__(1024, 4) void rowsum_kernel(
        const unsigned short* __restrict__ qkT, float* __restrict__ rowsuminv,
        unsigned short* __restrict__ etg, float* __restrict__ psum) {
    __shared__ unsigned short kt[3][256][64];    // 96 KB triple buffer (DMA)
    __shared__ unsigned short etile[16][32][40]; // 40 KB wave-private transpose
    __shared__ float red[2][8][2][16];           // 2 KB
    __shared__ float rls[64];
    const int gid = blockIdx.x;
    const int xcd = gid & 7;
    const int b = xcd >> 1;
    const int n0 = ((((unsigned)gid >> 3) << 1) | (xcd & 1)) * 64;
    const int tid = threadIdx.x;
    const int wave = tid >> 6, lane = tid & 63;
    const int nt = wave >> 3, ms = wave & 7;
    const int l31 = lane & 31, h = lane >> 5;
    const unsigned short* qb = qkT + (size_t)b * N_ * C4_;
    const int rowA = lane >> 3;
    const int swc = ((lane & 7) ^ rowA) * 8;
    const int w16 = wave * 16;
    const int r7 = l31 & 7;
    const unsigned short* qrow = qb + (size_t)(n0 + nt * 32 + l31) * C4_ + h * 8;
    bf16x8 qa[4];
#pragma unroll
    for (int j = 0; j < 4; ++j)
        qa[j] = *reinterpret_cast<const bf16x8*>(qrow + j * 16);
    asm volatile("s_waitcnt vmcnt(0)" ::: "memory");  // only DMAs+stores below
#define RS_STAGE(sidx, bufS)                                                  \
    do {                                                                      \
        g2l16(qb + (size_t)((sidx) * 256 + w16 + rowA) * C4_ + swc,           \
              &kt[bufS][w16][0]);                                             \
        g2l16(qb + (size_t)((sidx) * 256 + w16 + 8 + rowA) * C4_ + swc,       \
              &kt[bufS][w16 + 8][0]);                                         \
    } while (0)
    RS_STAGE(0, 0);
    RS_STAGE(1, 1);
    asm volatile("s_waitcnt vmcnt(2)" ::: "memory");
    __builtin_amdgcn_s_barrier();
    f32x16 acc = (f32x16){0.f, 0.f, 0.f, 0.f, 0.f, 0.f, 0.f, 0.f,
                          0.f, 0.f, 0.f, 0.f, 0.f, 0.f, 0.f, 0.f};
    int bufR = 0;
#pragma unroll 1
    for (int t = 0; t < 16; ++t) {
        if (t <= 13) {
            int bufS = bufR + 2; if (bufS >= 3) bufS -= 3;
            RS_STAGE(t + 2, bufS);
        }
        // e tile: D[row = n-local (r&3)+8*(r>>2)+4*h][col = m-local l31]
        f32x16 z = (f32x16){0.f, 0.f, 0.f, 0.f, 0.f, 0.f, 0.f, 0.f,
                            0.f, 0.f, 0.f, 0.f, 0.f, 0.f, 0.f, 0.f};
        __builtin_amdgcn_s_setprio(1);
#pragma unroll
        for (int j = 0; j < 4; ++j) {
            const bf16x8 kb = *reinterpret_cast<const bf16x8*>(
                &kt[bufR][ms * 32 + l31][(j * 16 + h * 8) ^ (r7 << 3)]);
            z = __builtin_amdgcn_mfma_f32_32x32x16_bf16(qa[j], kb, z, 0, 0, 0);
        }
        __builtin_amdgcn_s_setprio(0);
#pragma unroll
        for (int r = 0; r < 16; ++r) {
            const float ex = __expf(z[r]);
            acc[r] += ex;
            etile[wave][(r & 3) + 8 * (r >> 2) + 4 * h][l31] = bf16_rne(ex);
        }
        // transpose write-out of E~ (coalesced, full 64B lines per wave)
        asm volatile("s_waitcnt lgkmcnt(0)" ::: "memory");
        {
            const int r2 = lane >> 1, hf = lane & 1;
            const bf16x8 pr0 = *reinterpret_cast<const bf16x8*>(&etile[wave][r2][hf * 16]);
            const bf16x8 pr1 = *reinterpret_cast<const bf16x8*>(&etile[wave][r2][hf * 16 + 8]);
            unsigned short* pd = etg + ((size_t)b * N_ + n0 + nt * 32 + r2) * N_
                                 + t * 256 + ms * 32 + hf * 16;
            *reinterpret_cast<bf16x8*>(pd) = pr0;
            *reinterpret_cast<bf16x8*>(pd + 8) = pr1;
        }
        asm volatile("s_waitcnt lgkmcnt(0)" ::: "memory");
        if (t <= 13)      asm volatile("s_waitcnt vmcnt(4)" ::: "memory");
        else if (t == 14) asm volatile("s_waitcnt vmcnt(2)" ::: "memory");
        __builtin_amdgcn_s_barrier();
        ++bufR; if (bufR >= 3) bufR = 0;
    }
#undef RS_STAGE
    asm volatile("s_waitcnt vmcnt(0)" ::: "memory");  // all E~ stores retired
    // reduce over m: 32-lane xor groups (col = l31), then over 8 ms waves
#pragma unroll
    for (int r = 0; r < 16; ++r) {
        float s = acc[r];
#pragma unroll
        for (int k = 1; k <= 16; k <<= 1) s += __shfl_xor(s, k, 64);
        if (l31 == 0) red[nt][ms][h][r] = s;
    }
    __syncthreads();
    if (tid < 64) {
        const int v = tid & 31, nt2 = tid >> 5;
        const int reg = (v & 3) | ((v >> 3) << 2);
        const int hh = (v >> 2) & 1;
        float sum = 0.f;
#pragma unroll
        for (int m = 0; m < 8; ++m) sum += red[nt2][m][hh][reg];
        const float inv = 1.0f / sum;
        rowsuminv[(size_t)b * N_ + n0 + nt2 * 32 + v] = inv;
        rls[nt2 * 32 + v] = inv;
    }
    __syncthreads();
    // weighted column partials over own 64 rows (E~ block is L2-hot)
    float p0 = 0.f, p1 = 0.f, p2 = 0.f, p3 = 0.f;
    const unsigned short* eb = etg + ((size_t)b * N_ + n0) * N_ + tid * 4;
#pragma unroll 4
    for (int nn = 0; nn < 64; ++nn) {
        const float w = rls[nn];
        const ushort4 ev = *reinterpret_cast<const ushort4*>(eb + (size_t)nn * N_);
        p0 += bf16_to_f(ev.x) * w;
        p1 += bf16_to_f(ev.y) * w;
        p2 += bf16_to_f(ev.z) * w;
        p3 += bf16_to_f(ev.w) * w;
    }
    const float4 st = {p0, p1, p2, p3};
    *reinterpret_cast<float4*>(
        psum + ((size_t)b * 64 + (n0 >> 6)) * (size_t)N_ + tid * 4) = st;
}

// civ[b][m] = 1/(1e-9 + sum_blk psum[b][blk][m]).
__global__ __launch_bounds__(256) void civ_kernel(
        const float* __restrict__ psum, float* __restrict__ colsuminv) {
    const int idx = blockIdx.x * 256 + threadIdx.x;   // [0, 16384)
    const int b = idx >> 12, m = idx & 4095;
    const float* p = psum + (size_t)b * 64 * N_ + m;
    float s = 0.f;
#pragma unroll 8
    for (int k = 0; k < 64; ++k) s += p[(size_t)k * N_];
    colsuminv[(size_t)b * N_ + m] = 1.0f / (1e-9f + s);
}

// v~[b][c][m] = v[b][c][m] * colsuminv[b][m]  (in place, bf16).
__global__ __launch_bounds__(256) void scale_v_kernel(
        unsigned short* __restrict__ v, const float* __restrict__ colsuminv) {
    const size_t i8 = ((size_t)blockIdx.x * 256 + threadIdx.x) * 8;
    const int b = (int)(i8 >> 20);
    const int m = (int)(i8 & 4095);
    const float* cv = colsuminv + ((size_t)b << 12) + m;
    const float4 c0 = *reinterpret_cast<const float4*>(cv);
    const float4 c1 = *reinterpret_cast<const float4*>(cv + 4);
    const ushort4 a = *reinterpret_cast<const ushort4*>(v + i8);
    const ushort4 bb = *reinterpret_cast<const ushort4*>(v + i8 + 4);
    ushort4 oa, ob;
    oa.x = bf16_rne(bf16_to_f(a.x) * c0.x); oa.y = bf16_rne(bf16_to_f(a.y) * c0.y);
    oa.z = bf16_rne(bf16_to_f(a.z) * c0.z); oa.w = bf16_rne(bf16_to_f(a.w) * c0.w);
    ob.x = bf16_rne(bf16_to_f(bb.x) * c1.x); ob.y = bf16_rne(bf16_to_f(bb.y) * c1.y);
    ob.z = bf16_rne(bf16_to_f(bb.z) * c1.z); ob.w = bf16_rne(bf16_to_f(bb.w) * c1.w);
    *reinterpret_cast<ushort4*>(v + i8) = oa;
    *reinterpret_cast<ushort4*>(v + i8 + 4) = ob;
}

// Final v8 (pure GEMM): x_r = rsuminv[n] * (E~ . v~^T). DMA-staged E~-tile +
// v~-tile, triple-buffered, counted vmcnt, 1 barrier/iter. rsuminv applied
// once to the f32 accumulator in the epilogue.
__global__ __launch_bounds__(1024, 4) void final7_kernel(
        const float* __restrict__ x, const unsigned short* __restrict__ etg,
        const unsigned short* __restrict__ v, const unsigned short* __restrict__ wtb,
        const float* __restrict__ rowsuminv, const float* __restrict__ bt,
        const float* __restrict__ gamma, const float* __restrict__ beta,
        const float* __restrict__ rmean, const float* __restrict__ rvar,
        float* __restrict__ out) {
    __shared__ union {
        struct {
            unsigned short vt[3][256][64];                              // 96 KB
            unsigned short pt[3][64][64];                               // 24 KB
        } s;
        unsigned short dsm[64][268];                                    // 33.5 KB
    } u;
    const int gid = blockIdx.x;
    const int xcd = gid & 7;
    const int b = xcd >> 1;
    const int n0 = ((((unsigned)gid >> 3) << 1) | (xcd & 1)) * 64;
    const int tid = threadIdx.x;
    const int wave = tid >> 6, lane = tid & 63;
    const int ws = wave & 3, g = wave >> 2;
    const int quad = lane >> 4, l15 = lane & 15;
    const unsigned short* pb = etg + ((size_t)b * N_ + n0) * N_;
    const unsigned short* vbg = v + (size_t)b * C_ * N_;
    const int rowA = lane >> 3;
    const int swc = ((lane & 7) ^ rowA) * 8;
    const int w8 = wave * 8;
    const int r7 = l15 & 7;
    const int c0s = (quad * 8) ^ (r7 << 3);
    const int c1s = (32 + quad * 8) ^ (r7 << 3);
    const float4 rlv = *reinterpret_cast<const float4*>(
        rowsuminv + (size_t)b * N_ + n0 + ws * 16 + quad * 4);
    const float rlr[4] = {rlv.x, rlv.y, rlv.z, rlv.w};
    asm volatile("s_waitcnt vmcnt(0)" ::: "memory");  // only DMAs counted below
#define STAGE7(sidx, bufS)                                                              \
    do {                                                                                \
        g2l16(vbg + (size_t)(w8 + rowA) * N_ + (sidx) * 64 + swc,                       \
              &u.s.vt[bufS][w8][0]);                                                    \
        g2l16(vbg + (size_t)(w8 + 128 + rowA) * N_ + (sidx) * 64 + swc,                 \
              &u.s.vt[bufS][w8 + 128][0]);                                              \
        if (wave < 8)                                                                   \
            g2l16(pb + (size_t)(w8 + rowA) * N_ + (sidx) * 64 + swc,                    \
                  &u.s.pt[bufS][w8][0]);                                                \
    } while (0)
    STAGE7(0, 0);
    STAGE7(1, 1);
    if (wave < 8) asm volatile("s_waitcnt vmcnt(3)" ::: "memory");
    else          asm volatile("s_waitcnt vmcnt(2)" ::: "memory");
    __builtin_amdgcn_s_barrier();
    f32x4 acc[4];
#pragma unroll
    for (int j = 0; j < 4; ++j) acc[j] = (f32x4){0.f, 0.f, 0.f, 0.f};
    int bR = 0;
#pragma unroll 1
    for (int t = 0; t < 64; ++t) {
        if (t <= 61) {
            int bN2 = bR + 2; if (bN2 >= 3) bN2 -= 3;
            STAGE7(t + 2, bN2);
        }
        {
            const bf16x8 pa0 = *reinterpret_cast<const bf16x8*>(
                &u.s.pt[bR][ws * 16 + l15][c0s]);
            const bf16x8 pa1 = *reinterpret_cast<const bf16x8*>(
                &u.s.pt[bR][ws * 16 + l15][c1s]);
            const unsigned short(*vtb)[64] = u.s.vt[bR];
            __builtin_amdgcn_s_setprio(1);
#pragma unroll
            for (int j = 0; j < 4; ++j) {
                const int vr = (g * 4 + j) * 16 + l15;
                const bf16x8 vb0 = *reinterpret_cast<const bf16x8*>(&vtb[vr][c0s]);
                const bf16x8 vb1 = *reinterpret_cast<const bf16x8*>(&vtb[vr][c1s]);
                acc[j] = __builtin_amdgcn_mfma_f32_16x16x32_bf16(pa0, vb0, acc[j], 0, 0, 0);
                acc[j] = __builtin_amdgcn_mfma_f32_16x16x32_bf16(pa1, vb1, acc[j], 0, 0, 0);
            }
            __builtin_amdgcn_s_setprio(0);
        }
        asm volatile("s_waitcnt lgkmcnt(0)" ::: "memory");
        if (t <= 61) {
            if (wave < 8) asm volatile("s_waitcnt vmcnt(3)" ::: "memory");
            else          asm volatile("s_waitcnt vmcnt(2)" ::: "memory");
        } else if (t == 62) {
            asm volatile("s_waitcnt vmcnt(0)" ::: "memory");
        }
        __builtin_amdgcn_s_barrier();
        ++bR; if (bR >= 3) bR = 0;
    }
#undef STAGE7
    // dsm = x - rli*acc; acc[j][r] -> [n=ws*16+quad*4+r][c=(g*4+j)*16+l15]
#pragma unroll
    for (int j = 0; j < 4; ++j) {
        const int c = (g * 4 + j) * 16 + l15;
        const float4 xv = *reinterpret_cast<const float4*>(
            &x[((size_t)b * C_ + c) * N_ + n0 + ws * 16 + quad * 4]);
        const float xvr[4] = {xv.x, xv.y, xv.z, xv.w};
#pragma unroll
        for (int r = 0; r < 4; ++r)
            u.dsm[ws * 16 + quad * 4 + r][c] = bf16_rne(xvr[r] - acc[j][r] * rlr[r]);
    }
    __syncthreads();
    bf16x8 da[8];
#pragma unroll
    for (int k = 0; k < 8; ++k)
        da[k] = *reinterpret_cast<const bf16x8*>(&u.dsm[ws * 16 + l15][k * 32 + quad * 8]);
    f32x4 tacc[4];
#pragma unroll
    for (int j = 0; j < 4; ++j) tacc[j] = (f32x4){0.f, 0.f, 0.f, 0.f};
#pragma unroll
    for (int j = 0; j < 4; ++j) {
        const int ot = g * 4 + j;
#pragma unroll
        for (int k = 0; k < 8; ++k) {
            const bf16x8 wb = *reinterpret_cast<const bf16x8*>(
                wtb + (size_t)(ot * 16 + l15) * C_ + k * 32 + quad * 8);
            tacc[j] = __builtin_amdgcn_mfma_f32_16x16x32_bf16(da[k], wb, tacc[j], 0, 0, 0);
        }
    }
#pragma unroll
    for (int j = 0; j < 4; ++j) {
        const int o = (g * 4 + j) * 16 + l15;
        const float gg = gamma[o] * rsqrtf(rvar[o] + 1e-5f);
        const float mn = rmean[o], bbet = beta[o], bo = bt[o];
        const size_t oi = ((size_t)b * C_ + o) * N_ + n0 + ws * 16 + quad * 4;
        const float4 xo = *reinterpret_cast<const float4*>(&x[oi]);
        float4 res;
        res.x = xo.x + fmaxf((tacc[j][0] + bo - mn) * gg + bbet, 0.f);
        res.y = xo.y + fmaxf((tacc[j][1] + bo - mn) * gg + bbet, 0.f);
        res.z = xo.z + fmaxf((tacc[j][2] + bo - mn) * gg + bbet, 0.f);
        res.w = xo.w + fmaxf((tacc[j][3] + bo - mn) * gg + bbet, 0.f);
        *reinterpret_cast<float4*>(&out[oi]) = res;
    }
}

}  // namespace

extern "C" void kernel_launch(void* const* d_in, const int* in_sizes, int n_in,
                              void* d_out, int out_size, void* d_ws, size_t ws_size,
                              hipStream_t stream) {
    const float* x = (const float*)d_in[0];
    const float* wq = (const float*)d_in[1];
    const float* wv = (const float*)d_in[2];
    const float* bv = (const float*)d_in[3];
    const float* wt = (const float*)d_in[4];
    const float* bt = (const float*)d_in[5];
    const float* gamma = (const float*)d_in[6];
    const float* beta = (const float*)d_in[7];
    const float* rmean = (const float*)d_in[8];
    const float* rvar = (const float*)d_in[9];
    float* out = (float*)d_out;

    char* base = (char*)d_ws;
    unsigned short* qkT = (unsigned short*)base;                        // 2 MB
    unsigned short* vw = (unsigned short*)(base + (2u << 20));          // 8 MB
    unsigned short* wtb = (unsigned short*)(base + (10u << 20));        // 128 KB
    unsigned short* wfrag = (unsigned short*)(base + (10u << 20) + (128u << 10));
    float* rowsuminv = (float*)(base + (10u << 20) + (288u << 10));     // 64 KB
    float* colsuminv = (float*)(base + (10u << 20) + (352u << 10));     // 64 KB
    float* psum = (float*)(base + (11u << 20));                         // 4 MB
    unsigned short* etg = (unsigned short*)(base + (16ull << 20));      // 128 MB
    // ws_size >= 144 MB proven in round 9 (final7 path executed).

    cvt_kernel<<<dim3(144), dim3(256), 0, stream>>>(wq, wv, wt, wfrag, wtb);
    proj_kernel<<<dim3(N_ / 64, B_), dim3(1024), 0, stream>>>(x, wfrag, bv, qkT, vw);
    rowsum_kernel<<<dim3(N_ / 64 * B_), dim3(1024), 0, stream>>>(
        qkT, rowsuminv, etg, psum);
    civ_kernel<<<dim3(64), dim3(256), 0, stream>>>(psum, colsuminv);
    scale_v_kernel<<<dim3(2048), dim3(256), 0, stream>>>(vw, colsuminv);
    final7_kernel<<<dim3(N_ / 64 * B_), dim3(1024), 0, stream>>>(
        x, etg, vw, wtb, rowsuminv, bt, gamma, beta, rmean, rvar, out);
}